// Round 2
// baseline (837.224 us; speedup 1.0000x reference)
//
#include <hip/hip_runtime.h>

#define B 8
#define N 20000
#define M 256
#define I 64
#define O 64

// ---------------- Stage 1: dtx[b][m][i] = sum_n D[b][n][m] * x[b][n][i]
// grid (SPLIT, B), block 256. Thread owns 4 m x 16 i accumulators.
#define SPLIT 100
#define CHUNK (N / SPLIT)   // 200, divisible by 4

__global__ __launch_bounds__(256) void stage1(const float* __restrict__ Dg,
                                              const float* __restrict__ xg,
                                              float* __restrict__ dtx) {
    const int b = blockIdx.y;
    const int n0 = blockIdx.x * CHUNK;
    const int tid = threadIdx.x;
    const int m_base = (tid & 63) * 4;
    const int i_base = (tid >> 6) * 16;

    __shared__ float ldsD[4][M];
    __shared__ float ldsX[4][I];

    float acc[4][16];
#pragma unroll
    for (int a = 0; a < 4; ++a)
#pragma unroll
        for (int c = 0; c < 16; ++c) acc[a][c] = 0.f;

    const float* Dbase = Dg + (size_t)b * N * M;
    const float* xbase = xg + (size_t)b * N * I;

    for (int nt = 0; nt < CHUNK; nt += 4) {
        // stage 4 D rows (1024 floats) + 4 x rows (256 floats)
        {
            const int r = tid >> 6;          // 0..3
            const int c = (tid & 63) * 4;    // 0..252
            *(float4*)&ldsD[r][c] =
                *(const float4*)&Dbase[(size_t)(n0 + nt + r) * M + c];
            ldsX[r][tid & 63] = xbase[(size_t)(n0 + nt + r) * I + (tid & 63)];
        }
        __syncthreads();
#pragma unroll
        for (int nn = 0; nn < 4; ++nn) {
            float4 d4 = *(const float4*)&ldsD[nn][m_base];
            float xv[16];
            *(float4*)&xv[0]  = *(const float4*)&ldsX[nn][i_base + 0];
            *(float4*)&xv[4]  = *(const float4*)&ldsX[nn][i_base + 4];
            *(float4*)&xv[8]  = *(const float4*)&ldsX[nn][i_base + 8];
            *(float4*)&xv[12] = *(const float4*)&ldsX[nn][i_base + 12];
            const float dm[4] = {d4.x, d4.y, d4.z, d4.w};
#pragma unroll
            for (int a = 0; a < 4; ++a)
#pragma unroll
                for (int c = 0; c < 16; ++c)
                    acc[a][c] = fmaf(dm[a], xv[c], acc[a][c]);
        }
        __syncthreads();
    }

    float* outp = dtx + (size_t)b * M * I;
#pragma unroll
    for (int a = 0; a < 4; ++a)
#pragma unroll
        for (int c = 0; c < 16; ++c)
            atomicAdd(&outp[(size_t)(m_base + a) * I + i_base + c], acc[a][c]);
}

// ---------------- Stage 2: S[b][m][o] = (1/16) * sum_i coeff[o][i][m] * dtx[b][m][i]
__global__ __launch_bounds__(256) void stage2(const float* __restrict__ coeff,
                                              const float* __restrict__ dtx,
                                              float* __restrict__ S) {
    const int g = blockIdx.x * 256 + threadIdx.x;   // 0 .. B*O*M-1
    const int b = g >> 14;            // O*M = 16384
    const int rem = g & 16383;
    const int o = rem >> 8;
    const int m = rem & 255;
    const float* dt = dtx + (size_t)b * M * I + (size_t)m * I;
    const float* cf = coeff + (size_t)o * I * M + m;
    float acc = 0.f;
#pragma unroll 8
    for (int i = 0; i < I; ++i)
        acc = fmaf(cf[(size_t)i * M], dt[i], acc);
    S[(size_t)b * M * O + (size_t)m * O + o] = acc * 0.0625f;   // 1/sqrt(256)
}

// ---------------- Stage 3: out[b][n][o] = sum_m D[b][n][m] * S[b][m][o]
#define MC 32
#define NTILE 64
#define NBLK ((N + NTILE - 1) / NTILE)   // 313

__global__ __launch_bounds__(256) void stage3(const float* __restrict__ Dg,
                                              const float* __restrict__ Sg,
                                              float* __restrict__ outg) {
    const int b = blockIdx.y;
    const int n0 = blockIdx.x * NTILE;
    const int tid = threadIdx.x;
    const int nl = tid & 63;
    const int o_base = (tid >> 6) * 16;

    __shared__ float Dt[NTILE][MC + 1];   // [n][m], stride 33 -> 2-way max
    __shared__ float St[MC][O];           // [m][o]

    float acc[16];
#pragma unroll
    for (int j = 0; j < 16; ++j) acc[j] = 0.f;

    const float* Db = Dg + (size_t)b * N * M;
    const float* Sb = Sg + (size_t)b * M * O;

    for (int mc = 0; mc < M; mc += MC) {
#pragma unroll
        for (int r = 0; r < 2; ++r) {
            const int f = tid + r * 256;       // 0..511 float4 slots
            const int n_row = f >> 3;          // 0..63
            const int m_off = (f & 7) * 4;     // 0..28
            const int gn = min(n0 + n_row, N - 1);
            float4 d4 = *(const float4*)&Db[(size_t)gn * M + mc + m_off];
            Dt[n_row][m_off + 0] = d4.x;
            Dt[n_row][m_off + 1] = d4.y;
            Dt[n_row][m_off + 2] = d4.z;
            Dt[n_row][m_off + 3] = d4.w;
            // S chunk: contiguous copy of 2048 floats
            *(float4*)((float*)St + (size_t)f * 4) =
                *(const float4*)&Sb[(size_t)mc * O + (size_t)f * 4];
        }
        __syncthreads();
#pragma unroll
        for (int mm = 0; mm < MC; ++mm) {
            const float d = Dt[nl][mm];
            float sv[16];
            *(float4*)&sv[0]  = *(const float4*)&St[mm][o_base + 0];
            *(float4*)&sv[4]  = *(const float4*)&St[mm][o_base + 4];
            *(float4*)&sv[8]  = *(const float4*)&St[mm][o_base + 8];
            *(float4*)&sv[12] = *(const float4*)&St[mm][o_base + 12];
#pragma unroll
            for (int j = 0; j < 16; ++j)
                acc[j] = fmaf(d, sv[j], acc[j]);
        }
        __syncthreads();
    }

    const int gn = n0 + nl;
    if (gn < N) {
        float* op = outg + ((size_t)b * N + gn) * O + o_base;
        *(float4*)&op[0]  = make_float4(acc[0],  acc[1],  acc[2],  acc[3]);
        *(float4*)&op[4]  = make_float4(acc[4],  acc[5],  acc[6],  acc[7]);
        *(float4*)&op[8]  = make_float4(acc[8],  acc[9],  acc[10], acc[11]);
        *(float4*)&op[12] = make_float4(acc[12], acc[13], acc[14], acc[15]);
    }
}

extern "C" void kernel_launch(void* const* d_in, const int* in_sizes, int n_in,
                              void* d_out, int out_size, void* d_ws, size_t ws_size,
                              hipStream_t stream) {
    const float* Dg    = (const float*)d_in[0];
    const float* xg    = (const float*)d_in[1];
    const float* coeff = (const float*)d_in[2];
    float* outg = (float*)d_out;

    float* dtx = (float*)d_ws;                       // B*M*I floats = 512 KB
    float* S   = dtx + (size_t)B * M * I;            // B*M*O floats = 512 KB

    hipMemsetAsync(dtx, 0, (size_t)B * M * I * sizeof(float), stream);
    stage1<<<dim3(SPLIT, B), 256, 0, stream>>>(Dg, xg, dtx);
    stage2<<<dim3((B * O * M) / 256), 256, 0, stream>>>(coeff, dtx, S);
    stage3<<<dim3(NBLK, B), 256, 0, stream>>>(Dg, S, outg);
}

// Round 3
// 232.166 us; speedup vs baseline: 3.6061x; 3.6061x over previous
//
#include <hip/hip_runtime.h>

#define B 8
#define N 20000
#define M 256
#define I 64
#define O 64
#define MI (M * I)          // 16384
#define ROWS 8              // n-rows per double-buffer step

// ---------------- Stage 1: partial[s][b][j] = sum_{n in chunk} D[b,n,m]*x[b,n,i]
// Thread owns 4m x 16i accumulators. Partial layout j = (a*16+cc)*256 + tid
// (coalesced stores; reduce kernel untangles the mapping).
__global__ __launch_bounds__(256) void stage1(const float* __restrict__ Dg,
                                              const float* __restrict__ xg,
                                              float* __restrict__ partial,
                                              int chunk) {
    const int b = blockIdx.y;
    const int s = blockIdx.x;
    const int n0 = s * chunk;
    const int nend = min(n0 + chunk, N);
    const int tid = threadIdx.x;
    const int m_base = (tid & 63) * 4;
    const int i_base = (tid >> 6) * 16;

    __shared__ float ldsD[2][ROWS][M];
    __shared__ float ldsX[2][ROWS][I];

    float acc[4][16];
#pragma unroll
    for (int a = 0; a < 4; ++a)
#pragma unroll
        for (int cc = 0; cc < 16; ++cc) acc[a][cc] = 0.f;

    const float* Dbase = Dg + (size_t)b * N * M;
    const float* xbase = xg + (size_t)b * N * I;

    const int r  = tid >> 6;          // 0..3 (row group)
    const int dc = (tid & 63) * 4;    // D column (float4)
    const int xi = tid & 63;          // x column

    const int steps = (nend > n0) ? (nend - n0 + ROWS - 1) / ROWS : 0;

    float4 dA, dB;
    float  xA, xB;
    const float4 z4 = make_float4(0.f, 0.f, 0.f, 0.f);

    if (steps > 0) {
        // prefetch step 0
        {
            const int n1 = n0 + r, n2 = n0 + r + 4;
            dA = (n1 < nend) ? *(const float4*)&Dbase[(size_t)n1 * M + dc] : z4;
            dB = (n2 < nend) ? *(const float4*)&Dbase[(size_t)n2 * M + dc] : z4;
            xA = (n1 < nend) ? xbase[(size_t)n1 * I + xi] : 0.f;
            xB = (n2 < nend) ? xbase[(size_t)n2 * I + xi] : 0.f;
        }
        *(float4*)&ldsD[0][r][dc]     = dA;
        *(float4*)&ldsD[0][r + 4][dc] = dB;
        ldsX[0][r][xi]     = xA;
        ldsX[0][r + 4][xi] = xB;

        for (int t = 0; t < steps; ++t) {
            const int cur = t & 1;
            const bool more = (t + 1 < steps);
            if (more) {   // issue next step's global loads (overlap compute)
                const int base = n0 + (t + 1) * ROWS;
                const int n1 = base + r, n2 = base + r + 4;
                dA = (n1 < nend) ? *(const float4*)&Dbase[(size_t)n1 * M + dc] : z4;
                dB = (n2 < nend) ? *(const float4*)&Dbase[(size_t)n2 * M + dc] : z4;
                xA = (n1 < nend) ? xbase[(size_t)n1 * I + xi] : 0.f;
                xB = (n2 < nend) ? xbase[(size_t)n2 * I + xi] : 0.f;
            }
            __syncthreads();   // buf[cur] writes visible
#pragma unroll
            for (int nn = 0; nn < ROWS; ++nn) {
                float4 d4 = *(const float4*)&ldsD[cur][nn][m_base];
                float xv[16];
                *(float4*)&xv[0]  = *(const float4*)&ldsX[cur][nn][i_base + 0];
                *(float4*)&xv[4]  = *(const float4*)&ldsX[cur][nn][i_base + 4];
                *(float4*)&xv[8]  = *(const float4*)&ldsX[cur][nn][i_base + 8];
                *(float4*)&xv[12] = *(const float4*)&ldsX[cur][nn][i_base + 12];
                const float dm[4] = {d4.x, d4.y, d4.z, d4.w};
#pragma unroll
                for (int a = 0; a < 4; ++a)
#pragma unroll
                    for (int cc = 0; cc < 16; ++cc)
                        acc[a][cc] = fmaf(dm[a], xv[cc], acc[a][cc]);
            }
            __syncthreads();   // everyone done reading before next buf write
            if (more) {
                const int nxt = (t + 1) & 1;
                *(float4*)&ldsD[nxt][r][dc]     = dA;
                *(float4*)&ldsD[nxt][r + 4][dc] = dB;
                ldsX[nxt][r][xi]     = xA;
                ldsX[nxt][r + 4][xi] = xB;
            }
        }
    }

    float* p = partial + ((size_t)s * B + b) * MI;
#pragma unroll
    for (int a = 0; a < 4; ++a)
#pragma unroll
        for (int cc = 0; cc < 16; ++cc)
            p[((a * 16 + cc) << 8) + tid] = acc[a][cc];   // coalesced
}

// ---------------- Reduce: dtx[b][m][i] = sum_s partial[s][b][j(m,i)]
__global__ __launch_bounds__(256) void reduce_partials(const float* __restrict__ partial,
                                                       float* __restrict__ dtx,
                                                       int nsplit) {
    const int bb = blockIdx.y;
    const int j = blockIdx.x * 256 + threadIdx.x;   // 0..MI-1
    const float* p = partial + (size_t)bb * MI + j;
    float sum = 0.f;
    for (int s = 0; s < nsplit; ++s)
        sum += p[(size_t)s * B * MI];
    const int cidx = j >> 8;      // 0..63
    const int t    = j & 255;
    const int m = (t & 63) * 4 + (cidx >> 4);
    const int i = (t >> 6) * 16 + (cidx & 15);
    dtx[(size_t)bb * MI + m * I + i] = sum;
}

// ---------------- Stage 2: S[b][m][o] = (1/16) * sum_i coeff[o][i][m] * dtx[b][m][i]
__global__ __launch_bounds__(256) void stage2(const float* __restrict__ coeff,
                                              const float* __restrict__ dtx,
                                              float* __restrict__ S) {
    const int g = blockIdx.x * 256 + threadIdx.x;   // 0 .. B*O*M-1
    const int b = g >> 14;            // O*M = 16384
    const int rem = g & 16383;
    const int o = rem >> 8;
    const int m = rem & 255;
    const float* dt = dtx + (size_t)b * M * I + (size_t)m * I;
    const float* cf = coeff + (size_t)o * I * M + m;
    float acc = 0.f;
#pragma unroll 8
    for (int i = 0; i < I; ++i)
        acc = fmaf(cf[(size_t)i * M], dt[i], acc);
    S[(size_t)b * M * O + (size_t)m * O + o] = acc * 0.0625f;   // 1/sqrt(256)
}

// ---------------- Stage 3: out[b][n][o] = sum_m D[b][n][m] * S[b][m][o]
#define MC 32
#define NTILE 64
#define NBLK ((N + NTILE - 1) / NTILE)   // 313

__global__ __launch_bounds__(256) void stage3(const float* __restrict__ Dg,
                                              const float* __restrict__ Sg,
                                              float* __restrict__ outg) {
    const int b = blockIdx.y;
    const int n0 = blockIdx.x * NTILE;
    const int tid = threadIdx.x;
    const int nl = tid & 63;
    const int o_base = (tid >> 6) * 16;

    __shared__ float Dt[NTILE][MC + 1];   // [n][m], stride 33 -> 2-way max
    __shared__ float St[MC][O];           // [m][o]

    float acc[16];
#pragma unroll
    for (int j = 0; j < 16; ++j) acc[j] = 0.f;

    const float* Db = Dg + (size_t)b * N * M;
    const float* Sb = Sg + (size_t)b * M * O;

    for (int mc = 0; mc < M; mc += MC) {
#pragma unroll
        for (int r = 0; r < 2; ++r) {
            const int f = tid + r * 256;       // 0..511 float4 slots
            const int n_row = f >> 3;          // 0..63
            const int m_off = (f & 7) * 4;     // 0..28
            const int gn = min(n0 + n_row, N - 1);
            float4 d4 = *(const float4*)&Db[(size_t)gn * M + mc + m_off];
            Dt[n_row][m_off + 0] = d4.x;
            Dt[n_row][m_off + 1] = d4.y;
            Dt[n_row][m_off + 2] = d4.z;
            Dt[n_row][m_off + 3] = d4.w;
            // S chunk: contiguous copy of 2048 floats
            *(float4*)((float*)St + (size_t)f * 4) =
                *(const float4*)&Sb[(size_t)mc * O + (size_t)f * 4];
        }
        __syncthreads();
#pragma unroll
        for (int mm = 0; mm < MC; ++mm) {
            const float d = Dt[nl][mm];
            float sv[16];
            *(float4*)&sv[0]  = *(const float4*)&St[mm][o_base + 0];
            *(float4*)&sv[4]  = *(const float4*)&St[mm][o_base + 4];
            *(float4*)&sv[8]  = *(const float4*)&St[mm][o_base + 8];
            *(float4*)&sv[12] = *(const float4*)&St[mm][o_base + 12];
#pragma unroll
            for (int j = 0; j < 16; ++j)
                acc[j] = fmaf(d, sv[j], acc[j]);
        }
        __syncthreads();
    }

    const int gn = n0 + nl;
    if (gn < N) {
        float* op = outg + ((size_t)b * N + gn) * O + o_base;
        *(float4*)&op[0]  = make_float4(acc[0],  acc[1],  acc[2],  acc[3]);
        *(float4*)&op[4]  = make_float4(acc[4],  acc[5],  acc[6],  acc[7]);
        *(float4*)&op[8]  = make_float4(acc[8],  acc[9],  acc[10], acc[11]);
        *(float4*)&op[12] = make_float4(acc[12], acc[13], acc[14], acc[15]);
    }
}

extern "C" void kernel_launch(void* const* d_in, const int* in_sizes, int n_in,
                              void* d_out, int out_size, void* d_ws, size_t ws_size,
                              hipStream_t stream) {
    const float* Dg    = (const float*)d_in[0];
    const float* xg    = (const float*)d_in[1];
    const float* coeff = (const float*)d_in[2];
    float* outg = (float*)d_out;

    float* dtx     = (float*)d_ws;                   // B*MI floats = 512 KB
    float* S       = dtx + (size_t)B * MI;           // B*M*O floats = 512 KB
    float* partial = S + (size_t)B * M * O;          // split * B*MI floats

    // Choose split-K factor from available workspace (deterministic in ws_size).
    const size_t fixed = 2ull * B * MI * sizeof(float);
    const size_t per   = (size_t)B * MI * sizeof(float);   // 512 KB per slot
    int split = 1;
    if (ws_size > fixed) {
        size_t cap = (ws_size - fixed) / per;
        split = (int)(cap < 1 ? 1 : (cap > 100 ? 100 : cap));
    }
    int chunk = ((N + split - 1) / split + ROWS - 1) & ~(ROWS - 1);

    stage1<<<dim3(split, B), 256, 0, stream>>>(Dg, xg, partial, chunk);
    reduce_partials<<<dim3(MI / 256, B), 256, 0, stream>>>(partial, dtx, split);
    stage2<<<dim3((B * O * M) / 256), 256, 0, stream>>>(coeff, dtx, S);
    stage3<<<dim3(NBLK, B), 256, 0, stream>>>(Dg, S, outg);
}